// Round 5
// baseline (5115.508 us; speedup 1.0000x reference)
//
#include <hip/hip_runtime.h>
#include <stdint.h>

#define B_ 64
#define T_ 2048
#define H_ 256

typedef unsigned int u32;
typedef unsigned short u16;
typedef __attribute__((ext_vector_type(8))) short short8;
typedef __attribute__((ext_vector_type(4))) float f32x4;

// LDS tile: 16 rows x 256 bf16 cols, row stride 512 B, XOR-swizzled so the
// 64-lane ds_read_b128 at (row=lane&15, slice=(lane>>4)*8) is conflict-free
// (verified round 4: residual conflicts trace to h-writes only, ~2%).
#define SWZ(row, byte) (((row) * 512) + ((byte) ^ (((row) & 7) << 4)))

// packed f32x2 -> bf16x2 (RNE), single HW instr [T12, gfx950-verified]
static __device__ __forceinline__ u32 cvtpk(float a, float b) {
  u32 d;
  asm("v_cvt_pk_bf16_f32 %0, %1, %2" : "=v"(d) : "v"(a), "v"(b));
  return d;
}
static __device__ __forceinline__ uint4 pack8(float4 a, float4 b) {
  uint4 r;
  r.x = cvtpk(a.x, a.y); r.y = cvtpk(a.z, a.w);
  r.z = cvtpk(b.x, b.y); r.w = cvtpk(b.z, b.w);
  return r;
}
static __device__ __forceinline__ short8 as8(uint4 v) {
  return __builtin_bit_cast(short8, v);
}
// 1 - 2*rcp(e^{2x}+1): mul+mul+exp+add+rcp+fma (~6 VALU) vs IEEE-div ~15.
// v_rcp_f32 is ~1ulp f32 — far below bf16 output rounding. Saturates right:
// e->inf => rcp->0 => 1; e->0 => rcp(1)=1 => -1.
static __device__ __forceinline__ float fast_tanh(float x) {
  float e = __expf(2.0f * x);
  float r = __builtin_amdgcn_rcpf(e + 1.0f);
  return fmaf(-2.0f, r, 1.0f);
}

// wf[q][kc] = W[(wv*4+q)*16 + (lane&15)][kc*32 + (lane>>4)*8 .. +8] as bf16x8.
// Verified A-operand layout for mfma_f32_16x16x32_bf16 [learn_hip m89/m91].
static __device__ __forceinline__ void load_wfrag(const float* W, int wv, int bl,
                                                  int g, uint4 wf[4][8]) {
#pragma unroll
  for (int q = 0; q < 4; ++q) {
    const float* wr = W + (size_t)((wv * 4 + q) * 16 + bl) * H_ + g * 8;
#pragma unroll
    for (int kc = 0; kc < 8; ++kc) {
      float4 a = *(const float4*)(wr + kc * 32);
      float4 b = *(const float4*)(wr + kc * 32 + 4);
      wf[q][kc] = pack8(a, b);
    }
  }
}

// pre[row, j] = dot(X[row,:], W[j,:]) + bi[j] + bh[j]   (all f32 global)
// W fragments in VGPRs, X 16-row tiles staged f32->bf16 into swizzled LDS
// (double-buffered). In-place safe (X == pre for layer 1): tile rows are
// read/prefetched strictly before stored; WGs own disjoint rows.
__global__ __launch_bounds__(256, 2) void pre_mfma(const float* X, const float* W,
                                                   const float* bi, const float* bh,
                                                   float* P, int tpw) {
  __shared__ char sb_[2][8192];
  const int tid = threadIdx.x;
  const int lane = tid & 63, wv = tid >> 6;
  const int bl = lane & 15, g = lane >> 4;

  uint4 wf[4][8];
  load_wfrag(W, wv, bl, g, wf);
  float4 bias[4];
#pragma unroll
  for (int q = 0; q < 4; ++q) {
    const int j0 = (wv * 4 + q) * 16 + g * 4;
    float4 a = *(const float4*)(bi + j0);
    float4 c = *(const float4*)(bh + j0);
    bias[q].x = a.x + c.x; bias[q].y = a.y + c.y;
    bias[q].z = a.z + c.z; bias[q].w = a.w + c.w;
  }

  const size_t row0 = (size_t)blockIdx.x * tpw * 16;
  const int sr = tid >> 4, sc = (tid & 15) * 16;  // staging: row, col (16 f32)
  float4 s0, s1, s2, s3;
  {
    const float4* xs = (const float4*)(X + (row0 + sr) * H_ + sc);
    s0 = xs[0]; s1 = xs[1]; s2 = xs[2]; s3 = xs[3];
  }

  for (int i = 0; i < tpw; ++i) {
    char* sb = sb_[i & 1];
    *(uint4*)(sb + SWZ(sr, sc * 2)) = pack8(s0, s1);
    *(uint4*)(sb + SWZ(sr, sc * 2 + 16)) = pack8(s2, s3);
    __syncthreads();
    if (i + 1 < tpw) {  // prefetch next tile; consumed at next ds_write
      const float4* xn = (const float4*)(X + (row0 + (i + 1) * 16 + sr) * H_ + sc);
      s0 = xn[0]; s1 = xn[1]; s2 = xn[2]; s3 = xn[3];
    }
    uint4 hf[8];
#pragma unroll
    for (int kc = 0; kc < 8; ++kc)
      hf[kc] = *(const uint4*)(sb + SWZ(bl, kc * 64 + g * 16));
    f32x4 acc[4];
#pragma unroll
    for (int q = 0; q < 4; ++q) {
      acc[q] = (f32x4){0.f, 0.f, 0.f, 0.f};
#pragma unroll
      for (int kc = 0; kc < 8; ++kc)
        acc[q] = __builtin_amdgcn_mfma_f32_16x16x32_bf16(as8(wf[q][kc]), as8(hf[kc]),
                                                         acc[q], 0, 0, 0);
    }
#pragma unroll
    for (int q = 0; q < 4; ++q) {
      const int j0 = (wv * 4 + q) * 16 + g * 4;
      float4 o;
      o.x = acc[q][0] + bias[q].x; o.y = acc[q][1] + bias[q].y;
      o.z = acc[q][2] + bias[q].z; o.w = acc[q][3] + bias[q].w;
      *(float4*)(P + (row0 + i * 16 + bl) * H_ + j0) = o;
    }
    __syncthreads();  // all reads of sb_[i&1] done before iter i+2 rewrites it
  }
}

// h_t = tanh(pre[t] + Whh . h_{t-1}); 16 batch elements per WG (4 WGs).
// Critical path per step: ds_read h -> MFMA (2x4-deep split chains) ->
// tanh/pack -> ds_write h -> lgkmcnt(0) -> barrier. The f32 out-store and
// pre[t+2] prefetch issue AFTER the barrier (off the recurrence path, their
// issue overlaps the next step's ds_read latency).
// In-place safe (pre == out): pre[t] consumed at t-2; out[t] stored at t.
__global__ __launch_bounds__(256, 1) void rec_mfma(const float* pre, const float* W,
                                                   float* out) {
  __shared__ char hb_[2][8192];
  const int tid = threadIdx.x;
  const int lane = tid & 63, wv = tid >> 6;
  const int bl = lane & 15, g = lane >> 4;
  const int b0 = blockIdx.x * 16;

  uint4 wf[4][8];
  load_wfrag(W, wv, bl, g, wf);

  {  // h(-1) = 0
    uint4 z = make_uint4(0, 0, 0, 0);
    ((uint4*)hb_[0])[tid] = z; ((uint4*)hb_[0])[tid + 256] = z;
    ((uint4*)hb_[1])[tid] = z; ((uint4*)hb_[1])[tid + 256] = z;
  }

  const float* prow = pre + (size_t)(b0 + bl) * T_ * H_;
  float* orow = out + (size_t)(b0 + bl) * T_ * H_;
  float4 pr0[4], pr1[4];
#pragma unroll
  for (int q = 0; q < 4; ++q) {
    const int j0 = (wv * 4 + q) * 16 + g * 4;
    pr0[q] = *(const float4*)(prow + 0 * H_ + j0);
    pr1[q] = *(const float4*)(prow + 1 * H_ + j0);
  }
  __syncthreads();

  auto step = [&](int t, float4 (&pr)[4], char* rbuf, char* wbuf) {
    uint4 hf[8];
#pragma unroll
    for (int kc = 0; kc < 8; ++kc)
      hf[kc] = *(const uint4*)(rbuf + SWZ(bl, kc * 64 + g * 16));
    f32x4 accA[4], accB[4];
#pragma unroll
    for (int q = 0; q < 4; ++q) {
      accA[q] = (f32x4){0.f, 0.f, 0.f, 0.f};
      accB[q] = (f32x4){0.f, 0.f, 0.f, 0.f};
#pragma unroll
      for (int kc = 0; kc < 4; ++kc) {  // two 4-deep chains halve MFMA latency
        accA[q] = __builtin_amdgcn_mfma_f32_16x16x32_bf16(as8(wf[q][kc]),
                                                          as8(hf[kc]), accA[q], 0, 0, 0);
        accB[q] = __builtin_amdgcn_mfma_f32_16x16x32_bf16(as8(wf[q][kc + 4]),
                                                          as8(hf[kc + 4]), accB[q], 0, 0, 0);
      }
    }
    float v[16];
#pragma unroll
    for (int q = 0; q < 4; ++q) {
      const float* pq = (const float*)&pr[q];
#pragma unroll
      for (int e = 0; e < 4; ++e)
        v[q * 4 + e] = fast_tanh(accA[q][e] + accB[q][e] + pq[e]);
    }
#pragma unroll
    for (int q = 0; q < 4; ++q) {  // h for step t+1 (critical)
      uint2 hw;
      hw.x = cvtpk(v[q * 4 + 0], v[q * 4 + 1]);
      hw.y = cvtpk(v[q * 4 + 2], v[q * 4 + 3]);
      *(uint2*)(wbuf + SWZ(bl, ((wv * 4 + q) * 16 + g * 4) * 2)) = hw;
    }
    // one barrier per step; LDS-only drain so global prefetches stay in flight
    asm volatile("s_waitcnt lgkmcnt(0)" ::: "memory");
    __builtin_amdgcn_s_barrier();
    __builtin_amdgcn_sched_barrier(0);
    // off-critical-path: f32 output store + depth-2 pre prefetch
#pragma unroll
    for (int q = 0; q < 4; ++q) {
      const int j0 = (wv * 4 + q) * 16 + g * 4;
      float4 o;
      o.x = v[q * 4 + 0]; o.y = v[q * 4 + 1];
      o.z = v[q * 4 + 2]; o.w = v[q * 4 + 3];
      *(float4*)(orow + (size_t)t * H_ + j0) = o;
    }
    if (t + 2 < T_) {
#pragma unroll
      for (int q = 0; q < 4; ++q) {
        const int j0 = (wv * 4 + q) * 16 + g * 4;
        pr[q] = *(const float4*)(prow + (size_t)(t + 2) * H_ + j0);
      }
    }
  };

  for (int t = 0; t < T_; t += 2) {  // manual 2-unroll keeps pr rings in regs
    step(t, pr0, hb_[0], hb_[1]);
    step(t + 1, pr1, hb_[1], hb_[0]);
  }
}

extern "C" void kernel_launch(void* const* d_in, const int* in_sizes, int n_in,
                              void* d_out, int out_size, void* d_ws, size_t ws_size,
                              hipStream_t stream) {
  (void)in_sizes; (void)n_in; (void)out_size; (void)d_ws; (void)ws_size;
  const float* x    = (const float*)d_in[0];
  const float* Wih0 = (const float*)d_in[1];
  const float* Whh0 = (const float*)d_in[2];
  const float* bih0 = (const float*)d_in[3];
  const float* bhh0 = (const float*)d_in[4];
  const float* Wih1 = (const float*)d_in[5];
  const float* Whh1 = (const float*)d_in[6];
  const float* bih1 = (const float*)d_in[7];
  const float* bhh1 = (const float*)d_in[8];
  float* out = (float*)d_out;

  const int TPW = 8;                       // 16-row tiles per workgroup
  const int NWG = (B_ * T_) / (TPW * 16);  // 1024
  pre_mfma<<<dim3(NWG), dim3(256), 0, stream>>>(x, Wih0, bih0, bhh0, out, TPW);
  rec_mfma<<<dim3(B_ / 16), dim3(256), 0, stream>>>(out, Whh0, out);
  pre_mfma<<<dim3(NWG), dim3(256), 0, stream>>>(out, Wih1, bih1, bhh1, out, TPW);
  rec_mfma<<<dim3(B_ / 16), dim3(256), 0, stream>>>(out, Whh1, out);
}

// Round 6
// 3978.518 us; speedup vs baseline: 1.2858x; 1.2858x over previous
//
#include <hip/hip_runtime.h>
#include <stdint.h>

#define B_ 64
#define T_ 2048
#define H_ 256

typedef unsigned int u32;
typedef unsigned short u16;
typedef __attribute__((ext_vector_type(8))) short short8;
typedef __attribute__((ext_vector_type(4))) float f32x4;

// LDS tile: 16 rows x 256 bf16 cols, row stride 512 B, XOR-swizzled so the
// 64-lane ds_read_b128 at (row=lane&15, slice=(lane>>4)*8) is conflict-free
// (verified round 4: residual conflicts trace to h-writes only, ~2%).
#define SWZ(row, byte) (((row) * 512) + ((byte) ^ (((row) & 7) << 4)))

// packed f32x2 -> bf16x2 (RNE), single HW instr [T12, gfx950-verified]
static __device__ __forceinline__ u32 cvtpk(float a, float b) {
  u32 d;
  asm("v_cvt_pk_bf16_f32 %0, %1, %2" : "=v"(d) : "v"(a), "v"(b));
  return d;
}
static __device__ __forceinline__ uint4 pack8(float4 a, float4 b) {
  uint4 r;
  r.x = cvtpk(a.x, a.y); r.y = cvtpk(a.z, a.w);
  r.z = cvtpk(b.x, b.y); r.w = cvtpk(b.z, b.w);
  return r;
}
static __device__ __forceinline__ short8 as8(uint4 v) {
  return __builtin_bit_cast(short8, v);
}
// 1 - 2*rcp(e^{2x}+1); v_rcp_f32 ~1ulp << bf16 rounding; saturates correctly.
static __device__ __forceinline__ float fast_tanh(float x) {
  float e = __expf(2.0f * x);
  float r = __builtin_amdgcn_rcpf(e + 1.0f);
  return fmaf(-2.0f, r, 1.0f);
}

// wf[q][kc] = W[jrow][kc*32 + (lane>>4)*8 .. +8] as bf16x8 — verified
// A-operand layout for mfma_f32_16x16x32_bf16 [learn_hip m89/m91].
template <int NQ>
static __device__ __forceinline__ void load_wfrag(const float* W, int qbase, int bl,
                                                  int g, uint4 wf[NQ][8]) {
#pragma unroll
  for (int q = 0; q < NQ; ++q) {
    const float* wr = W + (size_t)((qbase + q) * 16 + bl) * H_ + g * 8;
#pragma unroll
    for (int kc = 0; kc < 8; ++kc) {
      float4 a = *(const float4*)(wr + kc * 32);
      float4 b = *(const float4*)(wr + kc * 32 + 4);
      wf[q][kc] = pack8(a, b);
    }
  }
}

// pre[row, j] = dot(X[row,:], W[j,:]) + bi[j] + bh[j]   (all f32 global)
// 256 threads, 4 waves, W fragments in VGPRs, X tiles staged f32->bf16 into
// swizzled LDS (double-buffered). ~50us each, near HBM roofline; unchanged.
__global__ __launch_bounds__(256, 2) void pre_mfma(const float* X, const float* W,
                                                   const float* bi, const float* bh,
                                                   float* P, int tpw) {
  __shared__ char sb_[2][8192];
  const int tid = threadIdx.x;
  const int lane = tid & 63, wv = tid >> 6;
  const int bl = lane & 15, g = lane >> 4;

  uint4 wf[4][8];
  load_wfrag<4>(W, wv * 4, bl, g, wf);
  float4 bias[4];
#pragma unroll
  for (int q = 0; q < 4; ++q) {
    const int j0 = (wv * 4 + q) * 16 + g * 4;
    float4 a = *(const float4*)(bi + j0);
    float4 c = *(const float4*)(bh + j0);
    bias[q].x = a.x + c.x; bias[q].y = a.y + c.y;
    bias[q].z = a.z + c.z; bias[q].w = a.w + c.w;
  }

  const size_t row0 = (size_t)blockIdx.x * tpw * 16;
  const int sr = tid >> 4, sc = (tid & 15) * 16;  // staging: row, col (16 f32)
  float4 s0, s1, s2, s3;
  {
    const float4* xs = (const float4*)(X + (row0 + sr) * H_ + sc);
    s0 = xs[0]; s1 = xs[1]; s2 = xs[2]; s3 = xs[3];
  }

  for (int i = 0; i < tpw; ++i) {
    char* sb = sb_[i & 1];
    *(uint4*)(sb + SWZ(sr, sc * 2)) = pack8(s0, s1);
    *(uint4*)(sb + SWZ(sr, sc * 2 + 16)) = pack8(s2, s3);
    __syncthreads();
    if (i + 1 < tpw) {  // prefetch next tile; consumed at next ds_write
      const float4* xn = (const float4*)(X + (row0 + (i + 1) * 16 + sr) * H_ + sc);
      s0 = xn[0]; s1 = xn[1]; s2 = xn[2]; s3 = xn[3];
    }
    uint4 hf[8];
#pragma unroll
    for (int kc = 0; kc < 8; ++kc)
      hf[kc] = *(const uint4*)(sb + SWZ(bl, kc * 64 + g * 16));
    f32x4 acc[4];
#pragma unroll
    for (int q = 0; q < 4; ++q) {
      acc[q] = (f32x4){0.f, 0.f, 0.f, 0.f};
#pragma unroll
      for (int kc = 0; kc < 8; ++kc)
        acc[q] = __builtin_amdgcn_mfma_f32_16x16x32_bf16(as8(wf[q][kc]), as8(hf[kc]),
                                                         acc[q], 0, 0, 0);
    }
#pragma unroll
    for (int q = 0; q < 4; ++q) {
      const int j0 = (wv * 4 + q) * 16 + g * 4;
      float4 o;
      o.x = acc[q][0] + bias[q].x; o.y = acc[q][1] + bias[q].y;
      o.z = acc[q][2] + bias[q].z; o.w = acc[q][3] + bias[q].w;
      *(float4*)(P + (row0 + i * 16 + bl) * H_ + j0) = o;
    }
    __syncthreads();  // all reads of sb_[i&1] done before iter i+2 rewrites it
  }
}

// h_t = tanh(pre[t] + Whh . h_{t-1}); 16 batch elements per WG (4 WGs).
// 512 threads = 8 waves = 2 waves/SIMD: each wave owns a 32-wide j-slice
// (halves per-wave serial work); the second wave per SIMD fills dependency
// stalls (round-5 evidence: step is latency-exposure-bound, ~50% stall at
// 1 wave/SIMD). Round-4 tail ordering restored (it measured 430 cyc better
// than round 5's phase-split): per q {tanh, pack, ds_write h, out store,
// prefetch}, then one lgkmcnt(0)+s_barrier. Global prefetches stay in
// flight across the barrier (LDS-only drain).
// In-place safe (pre == out): pre[t+2] loaded during step t, out[t] stored
// at step t; disjoint addresses, 2-step lead.
__global__ __launch_bounds__(512, 1) void rec_mfma(const float* pre, const float* W,
                                                   float* out) {
  __shared__ char hb_[2][8192];
  const int tid = threadIdx.x;
  const int lane = tid & 63, wv = tid >> 6;   // wv = 0..7
  const int bl = lane & 15, g = lane >> 4;
  const int b0 = blockIdx.x * 16;

  uint4 wf[2][8];
  load_wfrag<2>(W, wv * 2, bl, g, wf);

  {  // h(-1) = 0 ; 512 threads x 16B = one full 8KB buffer each
    uint4 z = make_uint4(0, 0, 0, 0);
    ((uint4*)hb_[0])[tid] = z;
    ((uint4*)hb_[1])[tid] = z;
  }

  const float* prow = pre + (size_t)(b0 + bl) * T_ * H_;
  float* orow = out + (size_t)(b0 + bl) * T_ * H_;
  float4 pr0[2], pr1[2];
#pragma unroll
  for (int q = 0; q < 2; ++q) {
    const int j0 = (wv * 2 + q) * 16 + g * 4;
    pr0[q] = *(const float4*)(prow + 0 * H_ + j0);
    pr1[q] = *(const float4*)(prow + 1 * H_ + j0);
  }
  __syncthreads();

  auto step = [&](int t, float4 (&pr)[2], char* rbuf, char* wbuf) {
    uint4 hf[8];
#pragma unroll
    for (int kc = 0; kc < 8; ++kc)
      hf[kc] = *(const uint4*)(rbuf + SWZ(bl, kc * 64 + g * 16));
    f32x4 accA[2], accB[2];
#pragma unroll
    for (int q = 0; q < 2; ++q) {
      accA[q] = (f32x4){0.f, 0.f, 0.f, 0.f};
      accB[q] = (f32x4){0.f, 0.f, 0.f, 0.f};
#pragma unroll
      for (int kc = 0; kc < 4; ++kc) {  // two 4-deep chains halve MFMA latency
        accA[q] = __builtin_amdgcn_mfma_f32_16x16x32_bf16(as8(wf[q][kc]),
                                                          as8(hf[kc]), accA[q], 0, 0, 0);
        accB[q] = __builtin_amdgcn_mfma_f32_16x16x32_bf16(as8(wf[q][kc + 4]),
                                                          as8(hf[kc + 4]), accB[q], 0, 0, 0);
      }
    }
#pragma unroll
    for (int q = 0; q < 2; ++q) {
      const int j0 = (wv * 2 + q) * 16 + g * 4;
      const float* pq = (const float*)&pr[q];
      float v0 = fast_tanh(accA[q][0] + accB[q][0] + pq[0]);
      float v1 = fast_tanh(accA[q][1] + accB[q][1] + pq[1]);
      float v2 = fast_tanh(accA[q][2] + accB[q][2] + pq[2]);
      float v3 = fast_tanh(accA[q][3] + accB[q][3] + pq[3]);
      uint2 hw; hw.x = cvtpk(v0, v1); hw.y = cvtpk(v2, v3);
      *(uint2*)(wbuf + SWZ(bl, j0 * 2)) = hw;            // h for step t+1
      float4 o; o.x = v0; o.y = v1; o.z = v2; o.w = v3;
      *(float4*)(orow + (size_t)t * H_ + j0) = o;        // off-path f32 out
      if (t + 2 < T_)                                     // depth-2 prefetch
        pr[q] = *(const float4*)(prow + (size_t)(t + 2) * H_ + j0);
    }
    // one barrier per step; LDS-only drain so global prefetches stay in flight
    asm volatile("s_waitcnt lgkmcnt(0)" ::: "memory");
    __builtin_amdgcn_s_barrier();
    __builtin_amdgcn_sched_barrier(0);
  };

  for (int t = 0; t < T_; t += 2) {  // manual 2-unroll keeps pr rings in regs
    step(t, pr0, hb_[0], hb_[1]);
    step(t + 1, pr1, hb_[1], hb_[0]);
  }
}

extern "C" void kernel_launch(void* const* d_in, const int* in_sizes, int n_in,
                              void* d_out, int out_size, void* d_ws, size_t ws_size,
                              hipStream_t stream) {
  (void)in_sizes; (void)n_in; (void)out_size; (void)d_ws; (void)ws_size;
  const float* x    = (const float*)d_in[0];
  const float* Wih0 = (const float*)d_in[1];
  const float* Whh0 = (const float*)d_in[2];
  const float* bih0 = (const float*)d_in[3];
  const float* bhh0 = (const float*)d_in[4];
  const float* Wih1 = (const float*)d_in[5];
  const float* Whh1 = (const float*)d_in[6];
  const float* bih1 = (const float*)d_in[7];
  const float* bhh1 = (const float*)d_in[8];
  float* out = (float*)d_out;

  const int TPW = 8;                       // 16-row tiles per workgroup
  const int NWG = (B_ * T_) / (TPW * 16);  // 1024
  pre_mfma<<<dim3(NWG), dim3(256), 0, stream>>>(x, Wih0, bih0, bhh0, out, TPW);
  rec_mfma<<<dim3(B_ / 16), dim3(512), 0, stream>>>(out, Whh0, out);
  pre_mfma<<<dim3(NWG), dim3(256), 0, stream>>>(out, Wih1, bih1, bhh1, out, TPW);
  rec_mfma<<<dim3(B_ / 16), dim3(512), 0, stream>>>(out, Whh1, out);
}